// Round 3
// baseline (996.580 us; speedup 1.0000x reference)
//
#include <hip/hip_runtime.h>
#include <stdint.h>

// CrossAttention seq-len-1: softmax over singleton == 1 ->
//   attn = x_other @ (out_w @ wv).T + (out_w @ bv + out_b)
// Pipeline: K1 per stream (attn GEMM + resid(fp32) + LN -> y bf16),
//           K2 per stream (FFN1 -> h in LDS chunks -> FFN2 + resid + LN -> fp32 out).
// Stripe kernels: A in padded LDS (no K-loop barriers), B b128 from L2-hot bf16 weights.
// Numerics match round-1 (absmax 0.031): residual/LN paths in fp32.

#define E 512
#define LNEPS 1e-5f
#define SX 520   // LDS stride for 512-wide bf16 tiles (pad 8 -> 2-way banks, free)
#define SHC 264  // LDS stride for 256-wide h-chunk

typedef unsigned short u16;
using u16x8   = __attribute__((ext_vector_type(8))) u16;
using u16x4   = __attribute__((ext_vector_type(4))) u16;
using shortx8 = __attribute__((ext_vector_type(8))) short;
using floatx4 = __attribute__((ext_vector_type(4))) float;

__device__ __forceinline__ float bf2f(u16 u) {
  uint32_t x = ((uint32_t)u) << 16;
  return __builtin_bit_cast(float, x);
}
__device__ __forceinline__ u16 f2bf(float f) {  // round-to-nearest-even
  uint32_t x = __builtin_bit_cast(uint32_t, f);
  x += 0x7fffu + ((x >> 16) & 1u);
  return (u16)(x >> 16);
}
__device__ __forceinline__ void gl_lds16(const u16* g, u16* l) {
  __builtin_amdgcn_global_load_lds(
      (__attribute__((address_space(1))) uint32_t*)g,
      (__attribute__((address_space(3))) uint32_t*)l, 16, 0, 0);
}

// ================= K1: attn projection + residual + LN =================
// y[r0+row, col] = LN( resid[row,col] + sum_k A[row,k]*W[col,k] + bias[col] )
// block: 32-row stripe, 8 waves; wave w owns cols w*64..w*64+63.
__global__ __launch_bounds__(512, 4) void attn_ln_kernel(
    const float* __restrict__ Araw, const float* __restrict__ resid,
    const u16* __restrict__ W, const float* __restrict__ bias,
    const float* __restrict__ g, const float* __restrict__ b,
    u16* __restrict__ Y) {
  __shared__ u16 sA[32 * SX];
  __shared__ float2 red[32][8];
  const int tid = threadIdx.x;
  const int w = tid >> 6, lane = tid & 63;
  const int fm = lane & 15, quad = lane >> 4;
  const int r0 = blockIdx.x * 32;

  // stage A rows (fp32 -> bf16 -> LDS)
  {
    const float* src = Araw + (size_t)r0 * E;
#pragma unroll
    for (int it = 0; it < 8; ++it) {
      const int e = it * 2048 + tid * 4;
      const int row = e >> 9, col = e & 511;
      const float4 v = *(const float4*)(src + e);
      u16x4 p;
      p[0] = f2bf(v.x); p[1] = f2bf(v.y); p[2] = f2bf(v.z); p[3] = f2bf(v.w);
      *(u16x4*)(&sA[row * SX + col]) = p;
    }
  }
  __syncthreads();

  const floatx4 zero = {0.f, 0.f, 0.f, 0.f};
  floatx4 acc[2][4];
#pragma unroll
  for (int i = 0; i < 2; ++i)
#pragma unroll
    for (int j = 0; j < 4; ++j) acc[i][j] = zero;

  const int ncol = w * 64;
#pragma unroll 4
  for (int k0 = 0; k0 < 512; k0 += 32) {
    const shortx8 a0 = *(const shortx8*)(&sA[(fm)*SX + k0 + quad * 8]);
    const shortx8 a1 = *(const shortx8*)(&sA[(16 + fm) * SX + k0 + quad * 8]);
#pragma unroll
    for (int j = 0; j < 4; ++j) {
      const shortx8 bf = *(const shortx8*)(W + (size_t)(ncol + j * 16 + fm) * 512 + k0 + quad * 8);
      acc[0][j] = __builtin_amdgcn_mfma_f32_16x16x32_bf16(a0, bf, acc[0][j], 0, 0, 0);
      acc[1][j] = __builtin_amdgcn_mfma_f32_16x16x32_bf16(a1, bf, acc[1][j], 0, 0, 0);
    }
  }

  // z = acc + bias + fp32 residual
  float bcol[4], gcol[4], bbcol[4];
#pragma unroll
  for (int j = 0; j < 4; ++j) {
    const int col = ncol + j * 16 + fm;
    bcol[j] = bias[col]; gcol[j] = g[col]; bbcol[j] = b[col];
  }
#pragma unroll
  for (int i = 0; i < 2; ++i)
#pragma unroll
    for (int rr = 0; rr < 4; ++rr) {
      const size_t rbase = (size_t)(r0 + i * 16 + quad * 4 + rr) * E;
#pragma unroll
      for (int j = 0; j < 4; ++j)
        acc[i][j][rr] += bcol[j] + resid[rbase + ncol + j * 16 + fm];
    }

  // cross-wave LN stats
#pragma unroll
  for (int i = 0; i < 2; ++i) {
    float s[4], q[4];
#pragma unroll
    for (int rr = 0; rr < 4; ++rr) {
      s[rr] = 0.f; q[rr] = 0.f;
#pragma unroll
      for (int j = 0; j < 4; ++j) {
        const float v = acc[i][j][rr];
        s[rr] += v; q[rr] += v * v;
      }
    }
#pragma unroll
    for (int m = 1; m < 16; m <<= 1)
#pragma unroll
      for (int rr = 0; rr < 4; ++rr) {
        s[rr] += __shfl_xor(s[rr], m);
        q[rr] += __shfl_xor(q[rr], m);
      }
    if (fm == 0)
#pragma unroll
      for (int rr = 0; rr < 4; ++rr)
        red[i * 16 + quad * 4 + rr][w] = make_float2(s[rr], q[rr]);
  }
  __syncthreads();

#pragma unroll
  for (int i = 0; i < 2; ++i)
#pragma unroll
    for (int rr = 0; rr < 4; ++rr) {
      const int row = i * 16 + quad * 4 + rr;
      float s = 0.f, q = 0.f;
#pragma unroll
      for (int ww = 0; ww < 8; ++ww) {
        const float2 t = red[row][ww];
        s += t.x; q += t.y;
      }
      const float mean = s * (1.f / 512.f);
      const float rs = rsqrtf(q * (1.f / 512.f) - mean * mean + LNEPS);
#pragma unroll
      for (int j = 0; j < 4; ++j) {
        const float y = (acc[i][j][rr] - mean) * rs * gcol[j] + bbcol[j];
        Y[(size_t)(r0 + row) * E + ncol + j * 16 + fm] = f2bf(y);
      }
    }
}

// ================= K2: FFN1 -> h chunks -> FFN2 + residual + LN =================
__global__ __launch_bounds__(512, 4) void ffn_ln_kernel(
    const u16* __restrict__ Y, const u16* __restrict__ W1, const float* __restrict__ B1,
    const u16* __restrict__ W2, const float* __restrict__ B2,
    const float* __restrict__ g, const float* __restrict__ b,
    float* __restrict__ out) {  // pre-offset for stream; ld = 1024
  __shared__ u16 sY[32 * SX];
  __shared__ u16 sH[32 * SHC];
  __shared__ float2 red[32][8];
  const int tid = threadIdx.x;
  const int w = tid >> 6, lane = tid & 63;
  const int fm = lane & 15, quad = lane >> 4;
  const int r0 = blockIdx.x * 32;

  // stage y (bf16 global -> LDS)
  {
    const u16* src = Y + (size_t)r0 * E;
#pragma unroll
    for (int it = 0; it < 4; ++it) {
      const int e = (it * 512 + tid) * 8;
      const int row = e >> 9, col = e & 511;
      *(u16x8*)(&sY[row * SX + col]) = *(const u16x8*)(src + e);
    }
  }
  __syncthreads();

  const floatx4 zero = {0.f, 0.f, 0.f, 0.f};
  floatx4 acc2[2][4];
#pragma unroll
  for (int i = 0; i < 2; ++i)
#pragma unroll
    for (int j = 0; j < 4; ++j) acc2[i][j] = zero;

#pragma unroll 1
  for (int c = 0; c < 4; ++c) {  // 256-wide h chunk
    floatx4 acc1[2][2];
#pragma unroll
    for (int i = 0; i < 2; ++i)
#pragma unroll
      for (int j = 0; j < 2; ++j) acc1[i][j] = zero;
#pragma unroll 2
    for (int k0 = 0; k0 < 512; k0 += 32) {
      const shortx8 a0 = *(const shortx8*)(&sY[(fm)*SX + k0 + quad * 8]);
      const shortx8 a1 = *(const shortx8*)(&sY[(16 + fm) * SX + k0 + quad * 8]);
#pragma unroll
      for (int j = 0; j < 2; ++j) {
        const int hr = c * 256 + w * 32 + j * 16 + fm;
        const shortx8 bf = *(const shortx8*)(W1 + (size_t)hr * 512 + k0 + quad * 8);
        acc1[0][j] = __builtin_amdgcn_mfma_f32_16x16x32_bf16(a0, bf, acc1[0][j], 0, 0, 0);
        acc1[1][j] = __builtin_amdgcn_mfma_f32_16x16x32_bf16(a1, bf, acc1[1][j], 0, 0, 0);
      }
    }
#pragma unroll
    for (int i = 0; i < 2; ++i)
#pragma unroll
      for (int j = 0; j < 2; ++j) {
        const int lcol = w * 32 + j * 16 + fm;
        const float bj = B1[c * 256 + lcol];
#pragma unroll
        for (int rr = 0; rr < 4; ++rr) {
          const int row = i * 16 + quad * 4 + rr;
          sH[row * SHC + lcol] = f2bf(fmaxf(acc1[i][j][rr] + bj, 0.f));
        }
      }
    __syncthreads();  // h chunk ready

#pragma unroll 2
    for (int kk = 0; kk < 256; kk += 32) {
      const shortx8 a0 = *(const shortx8*)(&sH[(fm)*SHC + kk + quad * 8]);
      const shortx8 a1 = *(const shortx8*)(&sH[(16 + fm) * SHC + kk + quad * 8]);
#pragma unroll
      for (int j = 0; j < 4; ++j) {
        const shortx8 bf =
            *(const shortx8*)(W2 + (size_t)(w * 64 + j * 16 + fm) * 1024 + c * 256 + kk + quad * 8);
        acc2[0][j] = __builtin_amdgcn_mfma_f32_16x16x32_bf16(a0, bf, acc2[0][j], 0, 0, 0);
        acc2[1][j] = __builtin_amdgcn_mfma_f32_16x16x32_bf16(a1, bf, acc2[1][j], 0, 0, 0);
      }
    }
    __syncthreads();  // before next chunk rewrites sH
  }

  // z2 = y(bf16) + acc2 + B2 ; LN -> fp32 out
  const int ncol = w * 64;
  float bcol[4], gcol[4], bbcol[4];
#pragma unroll
  for (int j = 0; j < 4; ++j) {
    const int col = ncol + j * 16 + fm;
    bcol[j] = B2[col]; gcol[j] = g[col]; bbcol[j] = b[col];
  }
#pragma unroll
  for (int i = 0; i < 2; ++i)
#pragma unroll
    for (int rr = 0; rr < 4; ++rr) {
      const int row = i * 16 + quad * 4 + rr;
#pragma unroll
      for (int j = 0; j < 4; ++j)
        acc2[i][j][rr] += bcol[j] + bf2f(sY[row * SX + ncol + j * 16 + fm]);
    }
#pragma unroll
  for (int i = 0; i < 2; ++i) {
    float s[4], q[4];
#pragma unroll
    for (int rr = 0; rr < 4; ++rr) {
      s[rr] = 0.f; q[rr] = 0.f;
#pragma unroll
      for (int j = 0; j < 4; ++j) {
        const float v = acc2[i][j][rr];
        s[rr] += v; q[rr] += v * v;
      }
    }
#pragma unroll
    for (int m = 1; m < 16; m <<= 1)
#pragma unroll
      for (int rr = 0; rr < 4; ++rr) {
        s[rr] += __shfl_xor(s[rr], m);
        q[rr] += __shfl_xor(q[rr], m);
      }
    if (fm == 0)
#pragma unroll
      for (int rr = 0; rr < 4; ++rr)
        red[i * 16 + quad * 4 + rr][w] = make_float2(s[rr], q[rr]);
  }
  __syncthreads();
#pragma unroll
  for (int i = 0; i < 2; ++i)
#pragma unroll
    for (int rr = 0; rr < 4; ++rr) {
      const int row = i * 16 + quad * 4 + rr;
      float s = 0.f, q = 0.f;
#pragma unroll
      for (int ww = 0; ww < 8; ++ww) {
        const float2 t = red[row][ww];
        s += t.x; q += t.y;
      }
      const float mean = s * (1.f / 512.f);
      const float rs = rsqrtf(q * (1.f / 512.f) - mean * mean + LNEPS);
#pragma unroll
      for (int j = 0; j < 4; ++j)
        out[(size_t)(r0 + row) * 1024 + ncol + j * 16 + fm] =
            (acc2[i][j][rr] - mean) * rs * gcol[j] + bbcol[j];
    }
}

// ================= weight-prep kernels (unchanged from round 1) =================
template <bool RELU, bool OUTF32>
__global__ __launch_bounds__(256) void gemm_bt(const u16* __restrict__ A,
                                               const u16* __restrict__ W,
                                               const float* __restrict__ bias,
                                               void* __restrict__ Cout,
                                               int M, int N, int K, int ldc) {
  __shared__ u16 sA[128 * 32];
  __shared__ u16 sB[128 * 32];
  const int tid = threadIdx.x;
  const int wave = tid >> 6;
  const int lane = tid & 63;
  const int m0 = blockIdx.x * 128;
  const int n0 = blockIdx.y * 128;
  const int wm = (wave >> 1) * 64;
  const int wn = (wave & 1) * 64;
  const int fm = lane & 15;
  const int quad = lane >> 4;

  const floatx4 zero = {0.f, 0.f, 0.f, 0.f};
  floatx4 acc[4][4];
#pragma unroll
  for (int i = 0; i < 4; ++i)
#pragma unroll
    for (int j = 0; j < 4; ++j) acc[i][j] = zero;

  const int o0 = wave * 512 + lane * 8;
  const int r0 = o0 >> 5;
  const int c0 = o0 & 31;
  const u16* Ap = A + (size_t)(m0 + r0) * K + c0;
  const u16* Wp = W + (size_t)(n0 + r0) * K + c0;
  const size_t skip = (size_t)64 * K;
  u16* sAd = sA + wave * 512;
  u16* sBd = sB + wave * 512;

  for (int k0 = 0; k0 < K; k0 += 32) {
    __syncthreads();
    gl_lds16(Ap, sAd);
    gl_lds16(Ap + skip, sAd + 2048);
    gl_lds16(Wp, sBd);
    gl_lds16(Wp + skip, sBd + 2048);
    Ap += 32;
    Wp += 32;
    __syncthreads();
    shortx8 af[4], bf[4];
#pragma unroll
    for (int i = 0; i < 4; ++i) {
      af[i] = *(const shortx8*)(sA + (wm + i * 16 + fm) * 32 + quad * 8);
      bf[i] = *(const shortx8*)(sB + (wn + i * 16 + fm) * 32 + quad * 8);
    }
#pragma unroll
    for (int i = 0; i < 4; ++i)
#pragma unroll
      for (int j = 0; j < 4; ++j)
        acc[i][j] = __builtin_amdgcn_mfma_f32_16x16x32_bf16(af[i], bf[j], acc[i][j], 0, 0, 0);
  }
#pragma unroll
  for (int j = 0; j < 4; ++j) {
    const int col = n0 + wn + j * 16 + fm;
    const float bj = bias ? bias[col] : 0.f;
#pragma unroll
    for (int i = 0; i < 4; ++i) {
      const int rb = m0 + wm + i * 16 + quad * 4;
#pragma unroll
      for (int r = 0; r < 4; ++r) {
        float v = acc[i][j][r] + bj;
        if (RELU) v = fmaxf(v, 0.f);
        if (OUTF32)
          ((float*)Cout)[(size_t)(rb + r) * ldc + col] = v;
        else
          ((u16*)Cout)[(size_t)(rb + r) * ldc + col] = f2bf(v);
      }
    }
  }
}

__global__ __launch_bounds__(256) void cast_kernel(const float* __restrict__ in,
                                                   u16* __restrict__ out) {
  const size_t i = ((size_t)blockIdx.x * 256 + threadIdx.x) * 8;
  const float4 a = *(const float4*)(in + i);
  const float4 c = *(const float4*)(in + i + 4);
  u16x8 o;
  o[0] = f2bf(a.x); o[1] = f2bf(a.y); o[2] = f2bf(a.z); o[3] = f2bf(a.w);
  o[4] = f2bf(c.x); o[5] = f2bf(c.y); o[6] = f2bf(c.z); o[7] = f2bf(c.w);
  *(u16x8*)(out + i) = o;
}

__global__ __launch_bounds__(256) void transpose_cast_kernel(const float* __restrict__ in,
                                                             u16* __restrict__ out) {
  __shared__ float t[32][33];
  const int bx = blockIdx.x * 32;
  const int by = blockIdx.y * 32;
  const int x = threadIdx.x & 31;
  const int y0 = threadIdx.x >> 5;
#pragma unroll
  for (int y = y0; y < 32; y += 8) t[y][x] = in[(size_t)(by + y) * E + bx + x];
  __syncthreads();
#pragma unroll
  for (int y = y0; y < 32; y += 8) out[(size_t)(bx + y) * E + by + x] = f2bf(t[x][y]);
}

__global__ __launch_bounds__(256) void combine_bias_kernel(const float* __restrict__ outw,
                                                           const float* __restrict__ bv,
                                                           const float* __restrict__ outb,
                                                           float* __restrict__ bc) {
  const int n = blockIdx.x * 256 + threadIdx.x;
  const float* wr = outw + (size_t)n * E;
  float s = 0.f;
  for (int j = 0; j < E; j += 4) {
    const float4 w4 = *(const float4*)(wr + j);
    const float4 v4 = *(const float4*)(bv + j);
    s += w4.x * v4.x + w4.y * v4.y + w4.z * v4.z + w4.w * v4.w;
  }
  bc[n] = s + outb[n];
}

extern "C" void kernel_launch(void* const* d_in, const int* in_sizes, int n_in,
                              void* d_out, int out_size, void* d_ws, size_t ws_size,
                              hipStream_t stream) {
  const float* dna      = (const float*)d_in[0];
  const float* mol      = (const float*)d_in[1];
  const float* a1_in_w  = (const float*)d_in[2];
  const float* a1_in_b  = (const float*)d_in[3];
  const float* a1_out_w = (const float*)d_in[4];
  const float* a1_out_b = (const float*)d_in[5];
  const float* a2_in_w  = (const float*)d_in[6];
  const float* a2_in_b  = (const float*)d_in[7];
  const float* a2_out_w = (const float*)d_in[8];
  const float* a2_out_b = (const float*)d_in[9];
  const float* ln1_g = (const float*)d_in[10];
  const float* ln1_b = (const float*)d_in[11];
  const float* ln2_g = (const float*)d_in[12];
  const float* ln2_b = (const float*)d_in[13];
  const float* ln3_g = (const float*)d_in[14];
  const float* ln3_b = (const float*)d_in[15];
  const float* ln4_g = (const float*)d_in[16];
  const float* ln4_b = (const float*)d_in[17];
  const float* f1_w1 = (const float*)d_in[18];
  const float* f1_b1 = (const float*)d_in[19];
  const float* f1_w2 = (const float*)d_in[20];
  const float* f1_b2 = (const float*)d_in[21];
  const float* f2_w1 = (const float*)d_in[22];
  const float* f2_b1 = (const float*)d_in[23];
  const float* f2_w2 = (const float*)d_in[24];
  const float* f2_b2 = (const float*)d_in[25];

  const int M = in_sizes[0] / E;  // 32768

  char* ws = (char*)d_ws;
  auto bump = [&](size_t sz) {
    char* p = ws;
    ws += (sz + 255) & ~(size_t)255;
    return p;
  };
  u16* wvT1   = (u16*)bump((size_t)E * E * 2);
  u16* wvT2   = (u16*)bump((size_t)E * E * 2);
  u16* outw1b = (u16*)bump((size_t)E * E * 2);
  u16* outw2b = (u16*)bump((size_t)E * E * 2);
  u16* Wc1    = (u16*)bump((size_t)E * E * 2);
  u16* Wc2    = (u16*)bump((size_t)E * E * 2);
  u16* fw11   = (u16*)bump((size_t)2 * E * E * 2);
  u16* fw12   = (u16*)bump((size_t)2 * E * E * 2);
  u16* fw21   = (u16*)bump((size_t)2 * E * E * 2);
  u16* fw22   = (u16*)bump((size_t)2 * E * E * 2);
  float* bc1  = (float*)bump(E * 4);
  float* bc2  = (float*)bump(E * 4);
  u16* X1 = (u16*)bump((size_t)M * E * 2);  // y1 bf16
  u16* X2 = (u16*)bump((size_t)M * E * 2);  // y2 bf16
  float* out_f = (float*)d_out;             // M x 1024

  // ---- weight prep ----
  transpose_cast_kernel<<<dim3(16, 16), 256, 0, stream>>>(a1_in_w + 2 * E * E, wvT1);
  transpose_cast_kernel<<<dim3(16, 16), 256, 0, stream>>>(a2_in_w + 2 * E * E, wvT2);
  cast_kernel<<<E * E / 2048, 256, 0, stream>>>(a1_out_w, outw1b);
  cast_kernel<<<E * E / 2048, 256, 0, stream>>>(a2_out_w, outw2b);
  cast_kernel<<<2 * E * E / 2048, 256, 0, stream>>>(f1_w1, fw11);
  cast_kernel<<<2 * E * E / 2048, 256, 0, stream>>>(f1_w2, fw12);
  cast_kernel<<<2 * E * E / 2048, 256, 0, stream>>>(f2_w1, fw21);
  cast_kernel<<<2 * E * E / 2048, 256, 0, stream>>>(f2_w2, fw22);
  combine_bias_kernel<<<2, 256, 0, stream>>>(a1_out_w, a1_in_b + 2 * E, a1_out_b, bc1);
  combine_bias_kernel<<<2, 256, 0, stream>>>(a2_out_w, a2_in_b + 2 * E, a2_out_b, bc2);
  gemm_bt<false, false><<<dim3(4, 4), 256, 0, stream>>>(outw1b, wvT1, nullptr, Wc1, E, E, E, E);
  gemm_bt<false, false><<<dim3(4, 4), 256, 0, stream>>>(outw2b, wvT2, nullptr, Wc2, E, E, E, E);

  // ---- K1: attn + residual + LN ----
  attn_ln_kernel<<<M / 32, 512, 0, stream>>>(mol, dna, Wc1, bc1, ln1_g, ln1_b, X1);
  attn_ln_kernel<<<M / 32, 512, 0, stream>>>(dna, mol, Wc2, bc2, ln2_g, ln2_b, X2);

  // ---- K2: FFN + residual + LN -> fp32 halves of d_out ----
  ffn_ln_kernel<<<M / 32, 512, 0, stream>>>(X1, fw11, f1_b1, fw12, f1_b2, ln3_g, ln3_b, out_f);
  ffn_ln_kernel<<<M / 32, 512, 0, stream>>>(X2, fw21, f2_b1, fw22, f2_b2, ln4_g, ln4_b, out_f + E);
}